// Round 12
// baseline (1337.179 us; speedup 1.0000x reference)
//
#include <hip/hip_runtime.h>
#include <math.h>

#define TS 10
#define TD 128
#define TE 64
#define BT 8
#define NTHR 256
#define HSTR 132          // floats per Hs row: 128+4 pad
#define QSTR 68           // floats per Q/K/Vd/G/t row: 64+4 pad
#define NHROWS (TS*BT)    // 80

#define HS_FLOATS (NHROWS*HSTR)    // 10560
#define WSCR 2160                  // per-wave scratch: Q 680 + K 680 + Vd 680 + P 120
#define LDS_FLOATS (HS_FLOATS + 4*WSCR)   // 19200 -> 76800 B (2 WG/CU)

#define INVSQRT10 0.31622776601683794f

// ---------------- POS precompute (fp64, once per launch, into d_ws) ----------
__global__ void pos_kernel(float* __restrict__ pos) {
    for (int idx = threadIdx.x; idx < TS * TD; idx += blockDim.x) {
        int n = idx / TD, d = idx % TD;
        int j = d >> 1;
        double ang = (double)n / pow(1000.0, 2.0 * (double)j / (double)TD);
        double v = (d & 1) ? cos(ang) : sin(ang);
        pos[idx] = (float)v;
    }
}

// ---------------- cross-wave M-row x C-col fp32 GEMM tile (ques phases) ------
template <int M, int SPLIT, int C, int K, bool ADD>
__device__ __forceinline__ void gemm_f32(
    const float* __restrict__ Ap, int a0, int aHi, int aLo,
    const float* __restrict__ W, int ws,
    float* __restrict__ Op, int o0, int oHi, int oLo,
    float scale)
{
    constexpr int CG = C / 4;
    float acc[M][C];
#pragma unroll
    for (int m = 0; m < M; m++)
#pragma unroll
        for (int c = 0; c < C; c++) acc[m][c] = 0.f;

    float4 aR0[M], aR1[M], wR0[4 * CG], wR1[4 * CG];
    const float* ap = Ap + a0;
    const float* wp = W;

    auto loadW = [&](float4* wR, const float* w) {
#pragma unroll
        for (int kk = 0; kk < 4; kk++)
#pragma unroll
            for (int cg = 0; cg < CG; cg++)
                wR[kk * CG + cg] = *(const float4*)(w + kk * ws + cg * 4);
    };
    auto loadA = [&](float4* aR, const float* a) {
#pragma unroll
        for (int m = 0; m < M; m++)
            aR[m] = *(const float4*)(a + (m / SPLIT) * aHi + (m % SPLIT) * aLo);
    };
    auto compute = [&](const float4* aR, const float4* wR) {
#pragma unroll
        for (int m = 0; m < M; m++) {
            const float* af = (const float*)&aR[m];
#pragma unroll
            for (int kk = 0; kk < 4; kk++) {
                float a = af[kk];
#pragma unroll
                for (int cg = 0; cg < CG; cg++) {
                    const float* wf = (const float*)&wR[kk * CG + cg];
#pragma unroll
                    for (int j = 0; j < 4; j++)
                        acc[m][cg * 4 + j] = fmaf(a, wf[j], acc[m][cg * 4 + j]);
                }
            }
        }
    };

    loadW(wR0, wp); loadA(aR0, ap);
#pragma unroll 1
    for (int k = 0; k + 8 < K; k += 8) {
        loadW(wR1, wp + 4 * ws); loadA(aR1, ap + 4);
        compute(aR0, wR0);
        wp += 8 * ws; ap += 8;
        loadW(wR0, wp); loadA(aR0, ap);
        compute(aR1, wR1);
    }
    loadW(wR1, wp + 4 * ws); loadA(aR1, ap + 4);
    compute(aR0, wR0);
    compute(aR1, wR1);

#pragma unroll
    for (int m = 0; m < M; m++) {
        float* op = Op + o0 + (m / SPLIT) * oHi + (m % SPLIT) * oLo;
#pragma unroll
        for (int cg = 0; cg < CG; cg++) {
            float4 r;
            if constexpr (ADD) {
                float4 v = *(float4*)(op + cg * 4);
                r.x = fmaf(scale, acc[m][cg * 4 + 0], v.x);
                r.y = fmaf(scale, acc[m][cg * 4 + 1], v.y);
                r.z = fmaf(scale, acc[m][cg * 4 + 2], v.z);
                r.w = fmaf(scale, acc[m][cg * 4 + 3], v.w);
            } else {
                r.x = scale * acc[m][cg * 4 + 0];
                r.y = scale * acc[m][cg * 4 + 1];
                r.z = scale * acc[m][cg * 4 + 2];
                r.w = scale * acc[m][cg * 4 + 3];
            }
            *(float4*)(op + cg * 4) = r;
        }
    }
}

// ---------------- fused kernel ----------------------------------------------
// Wave-private attention: wave w owns batches {2w, 2w+1}; QKV->logits->softmax
// ->G->DE run with ZERO barriers (in-order intra-wave LDS deps). Only the
// per-position ques projections (+ final out) mix batches -> 7 barriers total.
extern "C" __global__ __launch_bounds__(NTHR, 2)
void trans_fused(const float* __restrict__ x,
                 const float* __restrict__ L_w, const float* __restrict__ UL_w,
                 const float* __restrict__ WQ,  const float* __restrict__ WK,
                 const float* __restrict__ WVd, const float* __restrict__ WVu,
                 const float* __restrict__ WQ2, const float* __restrict__ WK2,
                 const float* __restrict__ WVd2,const float* __restrict__ WVu2,
                 const float* __restrict__ qin1,const float* __restrict__ qout1,
                 const float* __restrict__ qin2,const float* __restrict__ qout2,
                 const float* __restrict__ POSb, float* __restrict__ out)
{
    extern __shared__ float lds[];
    float* Hs  = lds;                    // [80][HSTR], row = b*10 + n
    float* Scr = lds + HS_FLOATS;        // 4 x WSCR per-wave scratch
    float* Tb  = Scr;                    // ques t overlay: [80][QSTR] (5440 <= 8640)

    const int tid = threadIdx.x;
    const int wv = tid >> 6, lane = tid & 63;
    const int vtid = (tid + ((blockIdx.x & 3) << 6)) & 255;
    const int gb0 = blockIdx.x * BT;

    float* Qw = Scr + wv * WSCR;         // [10][QSTR]; becomes G after logits
    float* Kw = Qw + 680;                // [10][QSTR]
    float* Vw = Qw + 1360;               // [10][QSTR]
    float* Pw = Qw + 2040;               // [10][12]

    // ---- Phase 0 (wave-local): h = x @ L_w + POS for own 2 batches ----
    for (int idx = lane; idx < 20 * TD; idx += 64) {
        int rr = idx >> 7, d = idx & 127;
        int r = wv * 20 + rr;
        int b = r / 10, n = r - b * 10;
        const float* xp = x + ((size_t)(gb0 + b) * TS + n) * 4;
        float acc = POSb[n * TD + d];
#pragma unroll
        for (int c = 0; c < 4; c++)
            acc = fmaf(xp[c], L_w[c * TD + d], acc);
        Hs[r * HSTR + d] = acc;
    }
    // no barrier: attention reads only this wave's rows

    for (int layer = 0; layer < 2; ++layer) {
        const float* pWQ  = layer ? WQ2  : WQ;
        const float* pWK  = layer ? WK2  : WK;
        const float* pWVd = layer ? WVd2 : WVd;
        const float* pWVu = layer ? WVu2 : WVu;
        const float* pqin = layer ? qin2 : qin1;
        const float* pqou = layer ? qout2 : qout1;

        // ======== wave-private attention over this wave's 2 batches ========
        for (int bs = 0; bs < 2; ++bs) {
            const int R0 = (wv * 2 + bs) * 10;

            // ---- Q,K: M=5 (row-half rh), C=2 (col-pair e2), dbuf K-loop ----
            {
                const int rh = lane >> 5, e2 = lane & 31;
                const float* ap = Hs + (R0 + rh * 5) * HSTR;
                const float* wq = pWQ + e2 * 2;
                const float* wk = pWK + e2 * 2;
                float accq[5][2], acck[5][2];
#pragma unroll
                for (int m = 0; m < 5; m++) {
                    accq[m][0] = accq[m][1] = 0.f;
                    acck[m][0] = acck[m][1] = 0.f;
                }
                float4 a0[5], a1[5];
                float2 q0[4], q1[4], k0[4], k1[4];
                auto ldA = [&](float4* a, const float* p) {
#pragma unroll
                    for (int m = 0; m < 5; m++) a[m] = *(const float4*)(p + m * HSTR);
                };
                auto ldW = [&](float2* d, const float* p) {
#pragma unroll
                    for (int kk = 0; kk < 4; kk++) d[kk] = *(const float2*)(p + kk * TE);
                };
                auto cmp = [&](const float4* a, const float2* qw, const float2* kw) {
#pragma unroll
                    for (int m = 0; m < 5; m++) {
                        const float* af = (const float*)&a[m];
#pragma unroll
                        for (int kk = 0; kk < 4; kk++) {
                            float av = af[kk];
                            accq[m][0] = fmaf(av, qw[kk].x, accq[m][0]);
                            accq[m][1] = fmaf(av, qw[kk].y, accq[m][1]);
                            acck[m][0] = fmaf(av, kw[kk].x, acck[m][0]);
                            acck[m][1] = fmaf(av, kw[kk].y, acck[m][1]);
                        }
                    }
                };
                ldA(a0, ap); ldW(q0, wq); ldW(k0, wk);
#pragma unroll 1
                for (int k = 0; k + 8 < TD; k += 8) {
                    ldA(a1, ap + 4); ldW(q1, wq + 4 * TE); ldW(k1, wk + 4 * TE);
                    cmp(a0, q0, k0);
                    ap += 8; wq += 8 * TE; wk += 8 * TE;
                    ldA(a0, ap); ldW(q0, wq); ldW(k0, wk);
                    cmp(a1, q1, k1);
                }
                ldA(a1, ap + 4); ldW(q1, wq + 4 * TE); ldW(k1, wk + 4 * TE);
                cmp(a0, q0, k0);
                cmp(a1, q1, k1);
#pragma unroll
                for (int m = 0; m < 5; m++) {
                    float2 vq, vk;
                    vq.x = accq[m][0]; vq.y = accq[m][1];
                    vk.x = acck[m][0]; vk.y = acck[m][1];
                    *(float2*)(Qw + (rh * 5 + m) * QSTR + e2 * 2) = vq;
                    *(float2*)(Kw + (rh * 5 + m) * QSTR + e2 * 2) = vk;
                }
            }

            // ---- Vd: M=5, C=2, single mat ----
            {
                const int rh = lane >> 5, e2 = lane & 31;
                const float* ap = Hs + (R0 + rh * 5) * HSTR;
                const float* wv2 = pWVd + e2 * 2;
                float acc[5][2];
#pragma unroll
                for (int m = 0; m < 5; m++) { acc[m][0] = acc[m][1] = 0.f; }
                float4 a0[5], a1[5];
                float2 w0[4], w1[4];
                auto ldA = [&](float4* a, const float* p) {
#pragma unroll
                    for (int m = 0; m < 5; m++) a[m] = *(const float4*)(p + m * HSTR);
                };
                auto ldW = [&](float2* d, const float* p) {
#pragma unroll
                    for (int kk = 0; kk < 4; kk++) d[kk] = *(const float2*)(p + kk * TE);
                };
                auto cmp = [&](const float4* a, const float2* w) {
#pragma unroll
                    for (int m = 0; m < 5; m++) {
                        const float* af = (const float*)&a[m];
#pragma unroll
                        for (int kk = 0; kk < 4; kk++) {
                            acc[m][0] = fmaf(af[kk], w[kk].x, acc[m][0]);
                            acc[m][1] = fmaf(af[kk], w[kk].y, acc[m][1]);
                        }
                    }
                };
                ldA(a0, ap); ldW(w0, wv2);
#pragma unroll 1
                for (int k = 0; k + 8 < TD; k += 8) {
                    ldA(a1, ap + 4); ldW(w1, wv2 + 4 * TE);
                    cmp(a0, w0);
                    ap += 8; wv2 += 8 * TE;
                    ldA(a0, ap); ldW(w0, wv2);
                    cmp(a1, w1);
                }
                ldA(a1, ap + 4); ldW(w1, wv2 + 4 * TE);
                cmp(a0, w0);
                cmp(a1, w1);
#pragma unroll
                for (int m = 0; m < 5; m++) {
                    float2 v; v.x = acc[m][0]; v.y = acc[m][1];
                    *(float2*)(Vw + (rh * 5 + m) * QSTR + e2 * 2) = v;
                }
            }

            // ---- logits (fp32, 2 chains): lanes 0..54 own (i, j<=i) ----
            if (lane < 55) {
                int pr = lane;
                int i = 0, base = 0;
                while (pr >= base + i + 1) { base += i + 1; i++; }
                int j = pr - base;
                const float* qr = Qw + i * QSTR;
                const float* kr = Kw + j * QSTR;
                float acc0 = 0.f, acc1 = 0.f;
                for (int e = 0; e < TE; e += 8) {
                    float4 qa = *(const float4*)(qr + e);
                    float4 ka = *(const float4*)(kr + e);
                    float4 qc = *(const float4*)(qr + e + 4);
                    float4 kc = *(const float4*)(kr + e + 4);
                    acc0 = fmaf(qa.x, ka.x, acc0);
                    acc1 = fmaf(qc.x, kc.x, acc1);
                    acc0 = fmaf(qa.y, ka.y, acc0);
                    acc1 = fmaf(qc.y, kc.y, acc1);
                    acc0 = fmaf(qa.z, ka.z, acc0);
                    acc1 = fmaf(qc.z, kc.z, acc1);
                    acc0 = fmaf(qa.w, ka.w, acc0);
                    acc1 = fmaf(qc.w, kc.w, acc1);
                }
                Pw[i * 12 + j] = acc0 + acc1;
            }

            // ---- softmax over keys j<=i (lanes 0..9) ----
            if (lane < 10) {
                float* pr = Pw + lane * 12;
                int i = lane;
                float m = pr[0];
#pragma unroll
                for (int j = 1; j < TS; j++) if (j <= i) m = fmaxf(m, pr[j]);
                float sum = 0.f;
#pragma unroll
                for (int j = 0; j < TS; j++) if (j <= i) { float e = expf(pr[j] - m); pr[j] = e; sum += e; }
#pragma unroll
                for (int j = 0; j < TS; j++) pr[j] = (j <= i) ? pr[j] / sum : 0.f;
            }

            // ---- G[q][e] = sum_k P[q][k] * Vd[k][e]; lane = e; into Qw ----
            {
                float vd[10];
#pragma unroll
                for (int k = 0; k < TS; k++) vd[k] = Vw[k * QSTR + lane];
#pragma unroll
                for (int q = 0; q < TS; q++) {
                    float g = 0.f;
#pragma unroll
                    for (int k = 0; k < TS; k++) g = fmaf(Pw[q * 12 + k], vd[k], g);
                    Qw[q * QSTR + lane] = g;
                }
            }

            // ---- DE: Hs[R0+q] += invsqrt10 * G @ WVu ; M=10, C=2 (lane=c2) ----
            {
                float acc[10][2];
#pragma unroll
                for (int m = 0; m < 10; m++) { acc[m][0] = acc[m][1] = 0.f; }
#pragma unroll 2
                for (int k = 0; k < TE; k += 4) {
                    float2 w[4];
#pragma unroll
                    for (int kk = 0; kk < 4; kk++)
                        w[kk] = *(const float2*)(pWVu + (size_t)(k + kk) * TD + lane * 2);
                    float4 a[10];
#pragma unroll
                    for (int m = 0; m < 10; m++)
                        a[m] = *(const float4*)(Qw + m * QSTR + k);
#pragma unroll
                    for (int m = 0; m < 10; m++) {
                        const float* af = (const float*)&a[m];
#pragma unroll
                        for (int kk = 0; kk < 4; kk++) {
                            acc[m][0] = fmaf(af[kk], w[kk].x, acc[m][0]);
                            acc[m][1] = fmaf(af[kk], w[kk].y, acc[m][1]);
                        }
                    }
                }
#pragma unroll
                for (int m = 0; m < 10; m++) {
                    float* hp = Hs + (R0 + m) * HSTR + lane * 2;
                    float2 v = *(float2*)hp;
                    v.x = fmaf(INVSQRT10, acc[m][0], v.x);
                    v.y = fmaf(INVSQRT10, acc[m][1], v.y);
                    *(float2*)hp = v;
                }
            }
        } // bs

        // ======== cross-batch ques projections (barriered) ========
        __syncthreads();   // all Hs rows final

        // ---- ques-in: t[80][64] = Hs @ quesin[n]; 160 = n(10) x cg(16), M=8 ----
        if (vtid < 160) {
            int n = vtid >> 4, cg = vtid & 15;
            gemm_f32<8, 1, 4, TD, false>(
                Hs, n * HSTR, 10 * HSTR, 0,
                pqin + (size_t)n * TD * TE + cg * 4, TE,
                Tb, n * QSTR + cg * 4, 10 * QSTR, 0, 1.f);
        }
        __syncthreads();

        // ---- ques-out: Hs = t @ quesout[n]; 320 = n(10) x cg(32), M=8 C=4 ----
        for (int task = vtid; task < 320; task += NTHR) {
            int n = task >> 5, cg = task & 31;
            gemm_f32<8, 1, 4, TE, false>(
                Tb, n * QSTR, 10 * QSTR, 0,
                pqou + (size_t)n * TE * TD + cg * 4, TD,
                Hs, n * HSTR + cg * 4, 10 * HSTR, 0, 1.f);
        }
        __syncthreads();   // Hs rewritten; next layer / out reads
    } // layer

    // ---- out = Hs @ UL_w : 320 outs, rotated grid-stride ----
    for (int idx = vtid; idx < NHROWS * 4; idx += NTHR) {
        int r = idx >> 2, c = idx & 3;
        int b = r / 10, n = r - b * 10;
        const float* hr = Hs + r * HSTR;
        float acc = 0.f;
        for (int d = 0; d < TD; d += 4) {
            float4 h4 = *(const float4*)(hr + d);
            acc = fmaf(h4.x, UL_w[(d + 0) * 4 + c], acc);
            acc = fmaf(h4.y, UL_w[(d + 1) * 4 + c], acc);
            acc = fmaf(h4.z, UL_w[(d + 2) * 4 + c], acc);
            acc = fmaf(h4.w, UL_w[(d + 3) * 4 + c], acc);
        }
        out[((size_t)(gb0 + b) * TS + n) * 4 + c] = acc;
    }
}

// ---------------- host launch -----------------------------------------------
extern "C" void kernel_launch(void* const* d_in, const int* in_sizes, int n_in,
                              void* d_out, int out_size, void* d_ws, size_t ws_size,
                              hipStream_t stream) {
    const float* x    = (const float*)d_in[0];
    const float* L_w  = (const float*)d_in[1];
    const float* UL_w = (const float*)d_in[2];
    const float* WQ   = (const float*)d_in[3];
    const float* WK   = (const float*)d_in[4];
    const float* WVd  = (const float*)d_in[5];
    const float* WVu  = (const float*)d_in[6];
    const float* WQ2  = (const float*)d_in[7];
    const float* WK2  = (const float*)d_in[8];
    const float* WVd2 = (const float*)d_in[9];
    const float* WVu2 = (const float*)d_in[10];
    const float* qin1 = (const float*)d_in[11];
    const float* qout1= (const float*)d_in[12];
    const float* qin2 = (const float*)d_in[13];
    const float* qout2= (const float*)d_in[14];
    float* out = (float*)d_out;
    float* POSb = (float*)d_ws;

    int B = in_sizes[0] / (TS * 4);
    size_t lds_bytes = (size_t)LDS_FLOATS * sizeof(float);

    (void)hipFuncSetAttribute((const void*)trans_fused,
                              hipFuncAttributeMaxDynamicSharedMemorySize,
                              (int)lds_bytes);

    pos_kernel<<<dim3(1), dim3(256), 0, stream>>>(POSb);
    trans_fused<<<dim3(B / BT), dim3(NTHR), lds_bytes, stream>>>(
        x, L_w, UL_w, WQ, WK, WVd, WVu, WQ2, WK2, WVd2, WVu2,
        qin1, qout1, qin2, qout2, POSb, out);
}

// Round 13
// 1055.988 us; speedup vs baseline: 1.2663x; 1.2663x over previous
//
#include <hip/hip_runtime.h>
#include <math.h>

#define TS 10
#define TD 128
#define TE 64
#define BT 8
#define NTHR 256
#define HSTR 132          // floats per Hs row: 128+4 pad
#define QSTR 68           // floats per Q/K/Vd/G/t row: 64+4 pad
#define NHROWS (TS*BT)    // 80

#define HS_FLOATS (NHROWS*HSTR)    // 10560
#define BUF_FLOATS (40*QSTR)       // 2720 (half-batch 40-row buffer)
#define P_FLOATS (BT*TS*12)        // 960
#define LDS_FLOATS (HS_FLOATS + 3*BUF_FLOATS + P_FLOATS)   // 19680 -> 78720 B (2 WG/CU)

#define INVSQRT10 0.31622776601683794f

typedef float v2f __attribute__((ext_vector_type(2)));

// ---------------- POS precompute (fp64, once per launch, into d_ws) ----------
__global__ void pos_kernel(float* __restrict__ pos) {
    for (int idx = threadIdx.x; idx < TS * TD; idx += blockDim.x) {
        int n = idx / TD, d = idx % TD;
        int j = d >> 1;
        double ang = (double)n / pow(1000.0, 2.0 * (double)j / (double)TD);
        double v = (d & 1) ? cos(ang) : sin(ang);
        pos[idx] = (float)v;
    }
}

// ---------------- M-row x C-col fp32 GEMM tile, packed-pair FMAs ------------
// OUT[m][c] = sum_k A[row(m)+k] * W[k*ws+c]. A,O in LDS; W in global.
// K multiple of 8, register double-buffered. Inner products expressed as
// float2 ext-vector ops so the backend forms v_pk_fma_f32 (2 IEEE fp32
// FMAs/lane/instr — bit-identical to scalar, half the issue slots).
template <int M, int SPLIT, int C, int K, bool ADD>
__device__ __forceinline__ void gemm_f32(
    const float* __restrict__ Ap, int a0, int aHi, int aLo,
    const float* __restrict__ W, int ws,
    float* __restrict__ Op, int o0, int oHi, int oLo,
    float scale)
{
    constexpr int CG = C / 4;   // float4 groups
    constexpr int CP = C / 2;   // float2 pairs
    v2f acc[M][CP];
#pragma unroll
    for (int m = 0; m < M; m++)
#pragma unroll
        for (int p = 0; p < CP; p++) acc[m][p] = (v2f)(0.f);

    float4 aR0[M], aR1[M], wR0[4 * CG], wR1[4 * CG];
    const float* ap = Ap + a0;
    const float* wp = W;

    auto loadW = [&](float4* wR, const float* w) {
#pragma unroll
        for (int kk = 0; kk < 4; kk++)
#pragma unroll
            for (int cg = 0; cg < CG; cg++)
                wR[kk * CG + cg] = *(const float4*)(w + kk * ws + cg * 4);
    };
    auto loadA = [&](float4* aR, const float* a) {
#pragma unroll
        for (int m = 0; m < M; m++)
            aR[m] = *(const float4*)(a + (m / SPLIT) * aHi + (m % SPLIT) * aLo);
    };
    auto compute = [&](const float4* aR, const float4* wR) {
#pragma unroll
        for (int m = 0; m < M; m++) {
            const float* af = (const float*)&aR[m];
#pragma unroll
            for (int kk = 0; kk < 4; kk++) {
                v2f av; av.x = af[kk]; av.y = af[kk];
                const v2f* wf = (const v2f*)&wR[kk * CG];
#pragma unroll
                for (int p = 0; p < CP; p++)
                    acc[m][p] = av * wf[p] + acc[m][p];   // v_pk_fma_f32
            }
        }
    };

    loadW(wR0, wp); loadA(aR0, ap);
#pragma unroll 1
    for (int k = 0; k + 8 < K; k += 8) {
        loadW(wR1, wp + 4 * ws); loadA(aR1, ap + 4);   // prefetch k+4
        compute(aR0, wR0);                              // compute k
        wp += 8 * ws; ap += 8;
        loadW(wR0, wp); loadA(aR0, ap);                 // prefetch k+8
        compute(aR1, wR1);                              // compute k+4
    }
    loadW(wR1, wp + 4 * ws); loadA(aR1, ap + 4);        // K-4
    compute(aR0, wR0);                                  // K-8
    compute(aR1, wR1);                                  // K-4

    v2f s2; s2.x = scale; s2.y = scale;
#pragma unroll
    for (int m = 0; m < M; m++) {
        float* op = Op + o0 + (m / SPLIT) * oHi + (m % SPLIT) * oLo;
#pragma unroll
        for (int cg = 0; cg < CG; cg++) {
            float4 r;
            v2f* rp = (v2f*)&r;
            if constexpr (ADD) {
                float4 v = *(float4*)(op + cg * 4);
                const v2f* vp = (const v2f*)&v;
                rp[0] = s2 * acc[m][cg * 2 + 0] + vp[0];
                rp[1] = s2 * acc[m][cg * 2 + 1] + vp[1];
            } else {
                rp[0] = s2 * acc[m][cg * 2 + 0];
                rp[1] = s2 * acc[m][cg * 2 + 1];
            }
            *(float4*)(op + cg * 4) = r;
        }
    }
}

// ---------------- fused kernel ----------------------------------------------
// BT=8, hb-split, 78.72 KB LDS -> 2 WG/CU. launch_bounds(256,2) caps VGPR at
// 128 (spill-free for all tiles used here; R10/R11-verified).
extern "C" __global__ __launch_bounds__(NTHR, 2)
void trans_fused(const float* __restrict__ x,
                 const float* __restrict__ L_w, const float* __restrict__ UL_w,
                 const float* __restrict__ WQ,  const float* __restrict__ WK,
                 const float* __restrict__ WVd, const float* __restrict__ WVu,
                 const float* __restrict__ WQ2, const float* __restrict__ WK2,
                 const float* __restrict__ WVd2,const float* __restrict__ WVu2,
                 const float* __restrict__ qin1,const float* __restrict__ qout1,
                 const float* __restrict__ qin2,const float* __restrict__ qout2,
                 const float* __restrict__ POSb, float* __restrict__ out)
{
    extern __shared__ float lds[];
    float* Hs = lds;                      // [80][HSTR], row = b*10 + n
    float* Qb = lds + HS_FLOATS;          // [40][QSTR], row r2 = b4*10 + n ; also G, t(lo)
    float* Kb = Qb + BUF_FLOATS;          // [40][QSTR]                     ; also t(hi)
    float* Vb = Kb + BUF_FLOATS;          // [40][QSTR] Vd
    float* Pb = Vb + BUF_FLOATS;          // [8][10][12] logits -> softmax weights
    float* Tb = Qb;                       // t: 80 rows spanning Qb+Kb

    const int tid = threadIdx.x;
    const int vtid = (tid + ((blockIdx.x & 3) << 6)) & 255;  // rotate idle windows
    const int gb0 = blockIdx.x * BT;

    // ---- Phase 0: h = x @ L_w + POS (fp32; 4-term dot) ----
    for (int idx = tid; idx < NHROWS * TD; idx += NTHR) {
        int r = idx >> 7, d = idx & 127;
        int b = r / 10, n = r - b * 10;
        const float* xp = x + ((size_t)(gb0 + b) * TS + n) * 4;
        float acc = POSb[n * TD + d];
#pragma unroll
        for (int c = 0; c < 4; c++)
            acc = fmaf(xp[c], L_w[c * TD + d], acc);
        Hs[r * HSTR + d] = acc;
    }
    __syncthreads();

    for (int layer = 0; layer < 2; ++layer) {
        const float* pWQ  = layer ? WQ2  : WQ;
        const float* pWK  = layer ? WK2  : WK;
        const float* pWVd = layer ? WVd2 : WVd;
        const float* pWVu = layer ? WVu2 : WVu;
        const float* pqin = layer ? qin2 : qin1;
        const float* pqou = layer ? qout2 : qout1;

        for (int hb = 0; hb < 2; ++hb) {
            // batches b = hb*4 + b4; Hs rows (hb*4+b4)*10 + n
            // ---- QKV: 240 tasks = mat(3) x np(5) x cg(16); M=8 = b4(4) x (n,n+5) ----
            if (vtid < 240) {
                int p = vtid / 80, t2 = vtid % 80;
                int np = t2 >> 4, cg = t2 & 15;
                const float* Wp = (p == 0 ? pWQ : (p == 1 ? pWK : pWVd)) + cg * 4;
                float* Ob = (p == 0 ? Qb : (p == 1 ? Kb : Vb));
                gemm_f32<8, 2, 4, TD, false>(
                    Hs, (hb * 40 + np) * HSTR, 10 * HSTR, 5 * HSTR,
                    Wp, TE,
                    Ob, np * QSTR + cg * 4, 10 * QSTR, 5 * QSTR, 1.f);
            }
            __syncthreads();

            // ---- logits (fp32, 2 chains): 220 = b4(4) x 55 (i,j<=i) ----
            if (vtid < 220) {
                int b4 = vtid / 55, pr = vtid % 55;
                int i = 0, base = 0;
                while (pr >= base + i + 1) { base += i + 1; i++; }
                int j = pr - base;
                const float* qr = Qb + (b4 * 10 + i) * QSTR;
                const float* kr = Kb + (b4 * 10 + j) * QSTR;
                float acc0 = 0.f, acc1 = 0.f;
                for (int e = 0; e < TE; e += 8) {
                    float4 qa = *(const float4*)(qr + e);
                    float4 ka = *(const float4*)(kr + e);
                    float4 qc = *(const float4*)(qr + e + 4);
                    float4 kc = *(const float4*)(kr + e + 4);
                    acc0 = fmaf(qa.x, ka.x, acc0);
                    acc1 = fmaf(qc.x, kc.x, acc1);
                    acc0 = fmaf(qa.y, ka.y, acc0);
                    acc1 = fmaf(qc.y, kc.y, acc1);
                    acc0 = fmaf(qa.z, ka.z, acc0);
                    acc1 = fmaf(qc.z, kc.z, acc1);
                    acc0 = fmaf(qa.w, ka.w, acc0);
                    acc1 = fmaf(qc.w, kc.w, acc1);
                }
                Pb[(hb * 4 + b4) * 120 + i * 12 + j] = acc0 + acc1;
            }
            __syncthreads();

            // ---- softmax over keys j<=i (fp32, matches reference) ----
            if (vtid < 40) {
                int b4 = vtid / 10, i = vtid % 10;
                float* pr = Pb + (hb * 4 + b4) * 120 + i * 12;
                float m = pr[0];
#pragma unroll
                for (int j = 1; j < TS; j++) if (j <= i) m = fmaxf(m, pr[j]);
                float sum = 0.f;
#pragma unroll
                for (int j = 0; j < TS; j++) if (j <= i) { float e = expf(pr[j] - m); pr[j] = e; sum += e; }
#pragma unroll
                for (int j = 0; j < TS; j++) pr[j] = (j <= i) ? pr[j] / sum : 0.f;
            }
            __syncthreads();

            // ---- G[r2=b4*10+q][e] = sum_k P * Vd[b4*10+k][e]; into Qb (Q dead) ----
            for (int oi = vtid; oi < 40 * 16; oi += NTHR) {
                int rr = oi >> 4, e4 = (oi & 15) * 4;
                int b4 = rr / 10, q = rr - b4 * 10;
                const float* pp = Pb + (hb * 4 + b4) * 120 + q * 12;
                float4 g = {0.f, 0.f, 0.f, 0.f};
#pragma unroll
                for (int k = 0; k < TS; k++) {
                    float p = pp[k];
                    float4 v = *(const float4*)(Vb + (b4 * 10 + k) * QSTR + e4);
                    g.x = fmaf(p, v.x, g.x);
                    g.y = fmaf(p, v.y, g.y);
                    g.z = fmaf(p, v.z, g.z);
                    g.w = fmaf(p, v.w, g.w);
                }
                *(float4*)(Qb + rr * QSTR + e4) = g;
            }
            __syncthreads();

            // ---- DE: Hs(half) += invsqrt10 * G @ WVu ----
            // 256 tasks exactly: b4(4) x qp(2) x cg(32); M=5 contiguous q rows.
            {
                int b4 = vtid >> 6, t2 = vtid & 63;
                int qp = t2 >> 5, cg = t2 & 31;
                gemm_f32<5, 5, 4, TE, true>(
                    Qb, (b4 * 10 + qp * 5) * QSTR, 0, QSTR,
                    pWVu + cg * 4, TD,
                    Hs, (hb * 40 + b4 * 10 + qp * 5) * HSTR + cg * 4, 0, HSTR,
                    INVSQRT10);
            }
            __syncthreads();
        } // hb

        // ---- ques-in: t[80][64] = Hs @ quesin[n]; 160 = n(10) x cg(16), M=8 over b ----
        if (vtid < 160) {
            int n = vtid >> 4, cg = vtid & 15;
            gemm_f32<8, 1, 4, TD, false>(
                Hs, n * HSTR, 10 * HSTR, 0,
                pqin + (size_t)n * TD * TE + cg * 4, TE,
                Tb, n * QSTR + cg * 4, 10 * QSTR, 0, 1.f);
        }
        __syncthreads();

        // ---- ques-out: Hs = t @ quesout[n]; 320 = n(10) x cg(32), M=8 C=4 ----
        for (int task = vtid; task < 320; task += NTHR) {
            int n = task >> 5, cg = task & 31;
            gemm_f32<8, 1, 4, TE, false>(
                Tb, n * QSTR, 10 * QSTR, 0,
                pqou + (size_t)n * TE * TD + cg * 4, TD,
                Hs, n * HSTR + cg * 4, 10 * HSTR, 0, 1.f);
        }
        __syncthreads();
    } // layer

    // ---- out = Hs @ UL_w : 320 outs, rotated grid-stride ----
    for (int idx = vtid; idx < NHROWS * 4; idx += NTHR) {
        int r = idx >> 2, c = idx & 3;
        int b = r / 10, n = r - b * 10;
        const float* hr = Hs + r * HSTR;
        float acc = 0.f;
        for (int d = 0; d < TD; d += 4) {
            float4 h4 = *(const float4*)(hr + d);
            acc = fmaf(h4.x, UL_w[(d + 0) * 4 + c], acc);
            acc = fmaf(h4.y, UL_w[(d + 1) * 4 + c], acc);
            acc = fmaf(h4.z, UL_w[(d + 2) * 4 + c], acc);
            acc = fmaf(h4.w, UL_w[(d + 3) * 4 + c], acc);
        }
        out[((size_t)(gb0 + b) * TS + n) * 4 + c] = acc;
    }
}

// ---------------- host launch -----------------------------------------------
extern "C" void kernel_launch(void* const* d_in, const int* in_sizes, int n_in,
                              void* d_out, int out_size, void* d_ws, size_t ws_size,
                              hipStream_t stream) {
    const float* x    = (const float*)d_in[0];
    const float* L_w  = (const float*)d_in[1];
    const float* UL_w = (const float*)d_in[2];
    const float* WQ   = (const float*)d_in[3];
    const float* WK   = (const float*)d_in[4];
    const float* WVd  = (const float*)d_in[5];
    const float* WVu  = (const float*)d_in[6];
    const float* WQ2  = (const float*)d_in[7];
    const float* WK2  = (const float*)d_in[8];
    const float* WVd2 = (const float*)d_in[9];
    const float* WVu2 = (const float*)d_in[10];
    const float* qin1 = (const float*)d_in[11];
    const float* qout1= (const float*)d_in[12];
    const float* qin2 = (const float*)d_in[13];
    const float* qout2= (const float*)d_in[14];
    float* out = (float*)d_out;
    float* POSb = (float*)d_ws;

    int B = in_sizes[0] / (TS * 4);
    size_t lds_bytes = (size_t)LDS_FLOATS * sizeof(float);

    (void)hipFuncSetAttribute((const void*)trans_fused,
                              hipFuncAttributeMaxDynamicSharedMemorySize,
                              (int)lds_bytes);

    pos_kernel<<<dim3(1), dim3(256), 0, stream>>>(POSb);
    trans_fused<<<dim3(B / BT), dim3(NTHR), lds_bytes, stream>>>(
        x, L_w, UL_w, WQ, WK, WVd, WVu, WQ2, WK2, WVd2, WVu2,
        qin1, qout1, qin2, qout2, POSb, out);
}